// Round 1
// baseline (474.007 us; speedup 1.0000x reference)
//
#include <hip/hip_runtime.h>
#include <hip/hip_bf16.h>

// ---------------------------------------------------------------------------
// Attention (B=2,N=2048,D=1024,H=16,DH=64) on gfx950.
// Pipeline:
//   1. split_x: x -> bf16 hi/lo pair (for f32-accurate score path)
//   2. transw:  W^T bf16 (hi, and lo for Wq/Wk)
//   3. gemm<SPLIT=1,EPI_QK>: q,k = rope(x@W+b), stored as bf16 hi/lo, [B,H,N,64]
//   4. gemm<SPLIT=0,EPI_V>:  v^T = (Wv^T)@(x^T), stored [B,H,64,N] (swapped-operand GEMM)
//   5. attn: flash attention, 3-term split QK^T (f32-accurate logits), bf16 PV
//   6. gemm<SPLIT=0,EPI_OUT>: out = (ctx@Wo + bo) * query_mask, f32
// Workspace use: 76 MiB.
// ---------------------------------------------------------------------------

typedef short bf16x8 __attribute__((ext_vector_type(8)));
typedef float f32x4 __attribute__((ext_vector_type(4)));

#define NEGBIG (-1.0e9f)

__device__ inline short f2bf(float x) {
  union { __hip_bfloat16 b; short s; } u;
  u.b = __float2bfloat16(x);
  return u.s;
}
__device__ inline float bf2f(short s) {
  union { short s; __hip_bfloat16 b; } u;
  u.s = s;
  return __bfloat162float(u.b);
}

__device__ inline f32x4 mfma16(bf16x8 a, bf16x8 b, f32x4 c) {
  return __builtin_amdgcn_mfma_f32_16x16x32_bf16(a, b, c, 0, 0, 0);
}

__device__ inline void gload16(const void* g, void* l) {
  __builtin_amdgcn_global_load_lds(
      (const __attribute__((address_space(1))) void*)g,
      (__attribute__((address_space(3))) void*)l, 16, 0, 0);
}

// -------------------------------- prep -------------------------------------

// x (f32, 4096x1024) -> xh, xl bf16 split. 1048576 float4's.
__global__ __launch_bounds__(256) void split_x_kernel(
    const float* __restrict__ x, short* __restrict__ xh, short* __restrict__ xl) {
  const int i = blockIdx.x * 256 + threadIdx.x;
  const float4 v = ((const float4*)x)[i];
  short h0 = f2bf(v.x), h1 = f2bf(v.y), h2 = f2bf(v.z), h3 = f2bf(v.w);
  short l0 = f2bf(v.x - bf2f(h0));
  short l1 = f2bf(v.y - bf2f(h1));
  short l2 = f2bf(v.z - bf2f(h2));
  short l3 = f2bf(v.w - bf2f(h3));
  ((short4*)xh)[i] = make_short4(h0, h1, h2, h3);
  ((short4*)xl)[i] = make_short4(l0, l1, l2, l3);
}

// W [1024 k][1024 j] f32 -> dh[j][k] bf16 (+ optional dl residual).
__global__ __launch_bounds__(256) void transw_kernel(
    const float* __restrict__ W, short* __restrict__ dh, short* __restrict__ dl) {
  __shared__ float tile[32][33];
  const int tx = threadIdx.x, ty = threadIdx.y;
  const int j0 = blockIdx.x * 32, k0 = blockIdx.y * 32;
  for (int i = ty; i < 32; i += 8)
    tile[i][tx] = W[(size_t)(k0 + i) * 1024 + j0 + tx];
  __syncthreads();
  for (int i = ty; i < 32; i += 8) {
    float v = tile[tx][i];
    size_t o = (size_t)(j0 + i) * 1024 + k0 + tx;
    short h = f2bf(v);
    dh[o] = h;
    if (dl) dl[o] = f2bf(v - bf2f(h));
  }
}

// -------------------------------- GEMM -------------------------------------
// C[m][j] = sum_k A[m][k] * B[j][k]  (both row-major with ld=1024)
// 128x128 tile, BK=32, 4 waves, 16x16x32 bf16 MFMA.
// SPLIT=1: 3-term hi/lo product for ~f32 accuracy.
// EPI 0: QK (bias+rope, split bf16 out to [2][B][H][N][64] hi/lo)
// EPI 1: V  (bias, bf16 out transposed [B][H][64][N]; here rows=j cols=m)
// EPI 2: OUT (bias + query mask, f32 out [m][j])

template <int SPLIT, int EPI>
__global__ __launch_bounds__(256) void gemm_kernel(
    const short* __restrict__ Asrc, const short* __restrict__ Alo,
    const short* __restrict__ Bsrc, const short* __restrict__ Blo,
    const float* __restrict__ biasA, const float* __restrict__ biasB,
    const float* __restrict__ ropeC, const float* __restrict__ ropeS,
    const int* __restrict__ lens,
    short* __restrict__ outH, short* __restrict__ outL,
    float* __restrict__ outF) {
  constexpr int NSLAB = SPLIT ? 4 : 2;
  __shared__ __align__(16) short smem[NSLAB * 4096];  // slabs of [128][32] bf16
  const int t = threadIdx.x;
  const int w = t >> 6, lane = t & 63;
  const int wr = w >> 1, wc = w & 1;
  const int fr = lane & 15, fg = lane >> 4;
  const int mtile = blockIdx.x, ntile = blockIdx.y;

  // staging: thread covers row (w*16 + lane/4), k-octet (lane%4)*8; 2 issues/slab
  const int srow = (w << 4) + (lane >> 2);
  const int skel = (lane & 3) << 3;
  const size_t aBase = (size_t)(mtile * 128 + srow) * 1024 + skel;
  const size_t bBase = (size_t)(ntile * 128 + srow) * 1024 + skel;
  const int ldst = (w << 9) + (lane << 3);  // shorts
  short* lA = &smem[0];
  short* lB = &smem[4096];

  f32x4 acc[4][4];
#pragma unroll
  for (int i = 0; i < 4; ++i)
#pragma unroll
    for (int j = 0; j < 4; ++j) {
      acc[i][j][0] = 0.f; acc[i][j][1] = 0.f; acc[i][j][2] = 0.f; acc[i][j][3] = 0.f;
    }

  for (int k0 = 0; k0 < 1024; k0 += 32) {
    gload16(Asrc + aBase + k0, lA + ldst);
    gload16(Asrc + aBase + k0 + 64 * 1024, lA + ldst + 2048);
    gload16(Bsrc + bBase + k0, lB + ldst);
    gload16(Bsrc + bBase + k0 + 64 * 1024, lB + ldst + 2048);
    if (SPLIT) {
      gload16(Alo + aBase + k0, lA + 8192 + ldst);
      gload16(Alo + aBase + k0 + 64 * 1024, lA + 8192 + ldst + 2048);
      gload16(Blo + bBase + k0, lB + 8192 + ldst);
      gload16(Blo + bBase + k0 + 64 * 1024, lB + 8192 + ldst + 2048);
    }
    __syncthreads();

    bf16x8 ah[4], bh[4], al[4], bl[4];
#pragma unroll
    for (int mi = 0; mi < 4; ++mi) {
      const int off = (wr * 64 + mi * 16 + fr) * 32 + fg * 8;
      ah[mi] = *(const bf16x8*)&lA[off];
      if (SPLIT) al[mi] = *(const bf16x8*)&lA[8192 + off];
    }
#pragma unroll
    for (int ni = 0; ni < 4; ++ni) {
      const int off = (wc * 64 + ni * 16 + fr) * 32 + fg * 8;
      bh[ni] = *(const bf16x8*)&lB[off];
      if (SPLIT) bl[ni] = *(const bf16x8*)&lB[8192 + off];
    }
#pragma unroll
    for (int mi = 0; mi < 4; ++mi)
#pragma unroll
      for (int ni = 0; ni < 4; ++ni) {
        acc[mi][ni] = mfma16(ah[mi], bh[ni], acc[mi][ni]);
        if (SPLIT) {
          acc[mi][ni] = mfma16(ah[mi], bl[ni], acc[mi][ni]);
          acc[mi][ni] = mfma16(al[mi], bh[ni], acc[mi][ni]);
        }
      }
    __syncthreads();
  }

  const int rowbase = mtile * 128 + wr * 64;
  const int colbase = ntile * 128 + wc * 64;

  if constexpr (EPI == 0) {
    // rows = tokens m, cols = j in [0,2048): which=q/k
#pragma unroll
    for (int ni = 0; ni < 4; ++ni) {
      const int gcol = colbase + ni * 16 + fr;
      const int which = gcol >> 10, jj = gcol & 1023;
      const int hh = jj >> 6, dd = jj & 63;
      const float bias = which ? biasB[jj] : biasA[jj];
#pragma unroll
      for (int mi = 0; mi < 4; ++mi) {
#pragma unroll
        for (int r = 0; r < 4; ++r) {
          const int grow = rowbase + mi * 16 + fg * 4 + r;
          const int b = grow >> 11, n = grow & 2047;
          float val = acc[mi][ni][r] + bias;
          float part = __shfl_xor(val, 1);
          const size_t ro = (size_t)(b * 2048 + n) * 1024 + jj;
          const float c = ropeC[ro], s = ropeS[ro];
          const float rot = (fr & 1) ? (val * c + part * s) : (val * c - part * s);
          const short hi = f2bf(rot);
          const short lo = f2bf(rot - bf2f(hi));
          const size_t dst =
              ((size_t)((which * 2 + b) * 16 + hh) * 2048 + n) * 64 + dd;
          outH[dst] = hi;
          outL[dst] = lo;
        }
      }
    }
  } else if constexpr (EPI == 1) {
    // rows = j (v output col), cols = tokens m; write v^T [B][H][64][N]
#pragma unroll
    for (int mi = 0; mi < 4; ++mi) {
#pragma unroll
      for (int r = 0; r < 4; ++r) {
        const int j = rowbase + mi * 16 + fg * 4 + r;
        const int hh = j >> 6, dd = j & 63;
        const float bias = biasA[j];
#pragma unroll
        for (int ni = 0; ni < 4; ++ni) {
          const int m = colbase + ni * 16 + fr;
          const int b = m >> 11, n = m & 2047;
          outH[((size_t)(b * 16 + hh) * 64 + dd) * 2048 + n] =
              f2bf(acc[mi][ni][r] + bias);
        }
      }
    }
  } else {
    // rows = tokens m, cols = j; f32 out with query mask
    const int b = rowbase >> 11;
    const int len = lens[b];
#pragma unroll
    for (int ni = 0; ni < 4; ++ni) {
      const int gcol = colbase + ni * 16 + fr;
      const float bias = biasA[gcol];
#pragma unroll
      for (int mi = 0; mi < 4; ++mi) {
#pragma unroll
        for (int r = 0; r < 4; ++r) {
          const int m = rowbase + mi * 16 + fg * 4 + r;
          const int n = m & 2047;
          float val = acc[mi][ni][r] + bias;
          if (n >= len) val = 0.f;
          outF[(size_t)m * 1024 + gcol] = val;
        }
      }
    }
  }
}

// ------------------------------ attention ----------------------------------
// grid: (32 qtiles of 64 rows, 32 bh). 4 waves/block, wave = 16 q rows.
// Online softmax, 32-key blocks. Logits: 3-term hi/lo split (f32-accurate).
__global__ __launch_bounds__(256) void attn_kernel(
    const short* __restrict__ qkh, const short* __restrict__ qkl,
    const short* __restrict__ vt, const int* __restrict__ lens,
    short* __restrict__ ctx) {
  __shared__ __align__(16) short plds[4][512];  // per-wave 16x32 bf16 P tile
  const int t = threadIdx.x;
  const int w = t >> 6, lane = t & 63;
  const int fr = lane & 15, fg = lane >> 4;
  const int qtile = blockIdx.x;
  const int bh = blockIdx.y;
  const int b = bh >> 4, h = bh & 15;
  const int len = lens[b];
  const int q0 = qtile * 64 + w * 16;

  const size_t qoff = (size_t)(b * 16 + h) * 2048 * 64;        // which=0
  const size_t koff = (size_t)((2 + b) * 16 + h) * 2048 * 64;  // which=1
  const size_t voff = (size_t)(b * 16 + h) * 64 * 2048;

  bf16x8 qh[2], ql[2];
#pragma unroll
  for (int s = 0; s < 2; ++s) {
    const size_t o = qoff + (size_t)(q0 + fr) * 64 + s * 32 + fg * 8;
    qh[s] = *(const bf16x8*)(qkh + o);
    ql[s] = *(const bf16x8*)(qkl + o);
  }

  f32x4 o_acc[4];
  float mrun[4], lrun[4];
#pragma unroll
  for (int dt = 0; dt < 4; ++dt) {
    o_acc[dt][0] = 0.f; o_acc[dt][1] = 0.f; o_acc[dt][2] = 0.f; o_acc[dt][3] = 0.f;
  }
#pragma unroll
  for (int r = 0; r < 4; ++r) { mrun[r] = -1e30f; lrun[r] = 0.f; }

  const int nkb = (len + 31) >> 5;
  for (int kb = 0; kb < nkb; ++kb) {
    const int key0 = kb * 32;
    f32x4 sacc[2];
#pragma unroll
    for (int ct = 0; ct < 2; ++ct) {
      sacc[ct][0] = 0.f; sacc[ct][1] = 0.f; sacc[ct][2] = 0.f; sacc[ct][3] = 0.f;
    }
#pragma unroll
    for (int ct = 0; ct < 2; ++ct) {
#pragma unroll
      for (int s = 0; s < 2; ++s) {
        const size_t o = koff + (size_t)(key0 + ct * 16 + fr) * 64 + s * 32 + fg * 8;
        const bf16x8 khf = *(const bf16x8*)(qkh + o);
        const bf16x8 klf = *(const bf16x8*)(qkl + o);
        sacc[ct] = mfma16(qh[s], khf, sacc[ct]);
        sacc[ct] = mfma16(ql[s], khf, sacc[ct]);
        sacc[ct] = mfma16(qh[s], klf, sacc[ct]);
      }
      const int keyj = key0 + ct * 16 + fr;
      if (keyj >= len) {
        sacc[ct][0] = NEGBIG; sacc[ct][1] = NEGBIG;
        sacc[ct][2] = NEGBIG; sacc[ct][3] = NEGBIG;
      }
    }
    // online softmax (rows live in 16-lane groups; row = fg*4 + r)
    float p0[4], p1[4], sc[4];
#pragma unroll
    for (int r = 0; r < 4; ++r) {
      float mx = fmaxf(sacc[0][r], sacc[1][r]);
      mx = fmaxf(mx, __shfl_xor(mx, 1, 16));
      mx = fmaxf(mx, __shfl_xor(mx, 2, 16));
      mx = fmaxf(mx, __shfl_xor(mx, 4, 16));
      mx = fmaxf(mx, __shfl_xor(mx, 8, 16));
      const float mnew = fmaxf(mrun[r], mx);
      sc[r] = __expf(mrun[r] - mnew);
      mrun[r] = mnew;
      p0[r] = __expf(sacc[0][r] - mnew);
      p1[r] = __expf(sacc[1][r] - mnew);
      float t2 = p0[r] + p1[r];
      t2 += __shfl_xor(t2, 1, 16);
      t2 += __shfl_xor(t2, 2, 16);
      t2 += __shfl_xor(t2, 4, 16);
      t2 += __shfl_xor(t2, 8, 16);
      lrun[r] = lrun[r] * sc[r] + t2;
    }
#pragma unroll
    for (int dt = 0; dt < 4; ++dt) {
      o_acc[dt][0] *= sc[0]; o_acc[dt][1] *= sc[1];
      o_acc[dt][2] *= sc[2]; o_acc[dt][3] *= sc[3];
    }
    // P -> bf16 -> wave-private LDS, reread as A-fragment
#pragma unroll
    for (int r = 0; r < 4; ++r) {
      plds[w][(fg * 4 + r) * 32 + fr] = f2bf(p0[r]);
      plds[w][(fg * 4 + r) * 32 + 16 + fr] = f2bf(p1[r]);
    }
    const bf16x8 pf = *(const bf16x8*)&plds[w][fr * 32 + fg * 8];
#pragma unroll
    for (int dt = 0; dt < 4; ++dt) {
      const size_t vo = voff + (size_t)(dt * 16 + fr) * 2048 + key0 + fg * 8;
      const bf16x8 vf = *(const bf16x8*)(vt + vo);
      o_acc[dt] = mfma16(pf, vf, o_acc[dt]);
    }
  }
  // ctx [B*N][1024] bf16
#pragma unroll
  for (int dt = 0; dt < 4; ++dt) {
#pragma unroll
    for (int r = 0; r < 4; ++r) {
      const int n = q0 + fg * 4 + r;
      ctx[(size_t)(b * 2048 + n) * 1024 + h * 64 + dt * 16 + fr] =
          f2bf(o_acc[dt][r] / lrun[r]);
    }
  }
}

// ------------------------------ launcher -----------------------------------

extern "C" void kernel_launch(void* const* d_in, const int* in_sizes, int n_in,
                              void* d_out, int out_size, void* d_ws, size_t ws_size,
                              hipStream_t stream) {
  const float* x = (const float*)d_in[0];
  const float* rc = (const float*)d_in[1];
  const float* rs = (const float*)d_in[2];
  const int* lens = (const int*)d_in[3];
  const float* Wq = (const float*)d_in[4];
  const float* bq = (const float*)d_in[5];
  const float* Wk = (const float*)d_in[6];
  const float* bk = (const float*)d_in[7];
  const float* Wv = (const float*)d_in[8];
  const float* bv = (const float*)d_in[9];
  const float* Wo = (const float*)d_in[10];
  const float* bo = (const float*)d_in[11];
  float* out = (float*)d_out;

  char* ws = (char*)d_ws;
  const size_t MB = 1024 * 1024;
  short* XH = (short*)(ws + 0);         // [4096][1024] bf16 hi   (8 MB)
  short* XL = (short*)(ws + 8 * MB);    // lo                     (8 MB)
  short* WTH = (short*)(ws + 16 * MB);  // [3072 j][1024 k] hi    (6 MB)
  short* WTL = (short*)(ws + 22 * MB);  // [2048 j][1024 k] lo    (4 MB)
  short* WOT = (short*)(ws + 26 * MB);  // [1024 j][1024 k]       (2 MB)
  short* QKH = (short*)(ws + 28 * MB);  // [2][2][16][2048][64] hi (16 MB)
  short* QKL = (short*)(ws + 44 * MB);  // lo                     (16 MB)
  short* VT = (short*)(ws + 60 * MB);   // [2][16][64][2048]      (8 MB)
  short* CTX = (short*)(ws + 68 * MB);  // [4096][1024]           (8 MB)

  split_x_kernel<<<4096, 256, 0, stream>>>(x, XH, XL);
  dim3 tb(32, 8), tg(32, 32);
  transw_kernel<<<tg, tb, 0, stream>>>(Wq, WTH, WTL);
  transw_kernel<<<tg, tb, 0, stream>>>(Wk, WTH + 1024 * 1024, WTL + 1024 * 1024);
  transw_kernel<<<tg, tb, 0, stream>>>(Wv, WTH + 2048 * 1024, nullptr);
  transw_kernel<<<tg, tb, 0, stream>>>(Wo, WOT, nullptr);

  // q,k = rope(x@W + b), split bf16
  gemm_kernel<1, 0><<<dim3(32, 16), 256, 0, stream>>>(
      XH, XL, WTH, WTL, bq, bk, rc, rs, nullptr, QKH, QKL, nullptr);
  // v^T = Wv^T @ x^T  (swapped operands -> transposed, coalesced output)
  gemm_kernel<0, 1><<<dim3(8, 32), 256, 0, stream>>>(
      WTH + (size_t)2048 * 1024, nullptr, XH, nullptr, bv, nullptr, nullptr,
      nullptr, nullptr, VT, nullptr, nullptr);
  attn_kernel<<<dim3(32, 32), 256, 0, stream>>>(QKH, QKL, VT, lens, CTX);
  // out = (ctx @ Wo + bo) * query-mask
  gemm_kernel<0, 2><<<dim3(32, 8), 256, 0, stream>>>(
      CTX, nullptr, WOT, nullptr, bo, nullptr, nullptr, nullptr, lens, nullptr,
      nullptr, out);
}

// Round 2
// 266.870 us; speedup vs baseline: 1.7762x; 1.7762x over previous
//
#include <hip/hip_runtime.h>
#include <hip/hip_bf16.h>

// ---------------------------------------------------------------------------
// Attention (B=2,N=2048,D=1024,H=16,DH=64) on gfx950.
//   1. split_x: x -> bf16 hi/lo pair (for f32-accurate score path)
//   2. transw:  W^T bf16 (hi, and lo for Wq/Wk)
//   3. gemm<1,0>: q,k = rope(x@W+b), q pre-scaled by log2e, bf16 hi/lo out
//   4. gemm<0,1>: v^T = (Wv^T)@(x^T) -> [B,H,64,N]
//   5. attn: flash attn; swapped QK^T (lane-local softmax rows), LDS-staged
//      K/V (double-buffered, global_load_lds, XOR-swizzled), defer-max,
//      log2-domain softmax, packed-P LDS relayout.
//   6. gemm<0,2>: out = (ctx@Wo + bo) * query_mask, f32
// ---------------------------------------------------------------------------

typedef short bf16x8 __attribute__((ext_vector_type(8)));
typedef float f32x4 __attribute__((ext_vector_type(4)));

#define NEGBIG (-1.0e9f)

__device__ inline short f2bf(float x) {
  union { __hip_bfloat16 b; short s; } u;
  u.b = __float2bfloat16(x);
  return u.s;
}
__device__ inline float bf2f(short s) {
  union { short s; __hip_bfloat16 b; } u;
  u.s = s;
  return __bfloat162float(u.b);
}
__device__ inline unsigned pack2(float a, float b) {
  return (unsigned)(unsigned short)f2bf(a) |
         ((unsigned)(unsigned short)f2bf(b) << 16);
}

__device__ inline f32x4 mfma16(bf16x8 a, bf16x8 b, f32x4 c) {
  return __builtin_amdgcn_mfma_f32_16x16x32_bf16(a, b, c, 0, 0, 0);
}

__device__ inline void gload16(const void* g, void* l) {
  __builtin_amdgcn_global_load_lds(
      (const __attribute__((address_space(1))) void*)g,
      (__attribute__((address_space(3))) void*)l, 16, 0, 0);
}

// -------------------------------- prep -------------------------------------

__global__ __launch_bounds__(256) void split_x_kernel(
    const float* __restrict__ x, short* __restrict__ xh, short* __restrict__ xl) {
  const int i = blockIdx.x * 256 + threadIdx.x;
  const float4 v = ((const float4*)x)[i];
  short h0 = f2bf(v.x), h1 = f2bf(v.y), h2 = f2bf(v.z), h3 = f2bf(v.w);
  short l0 = f2bf(v.x - bf2f(h0));
  short l1 = f2bf(v.y - bf2f(h1));
  short l2 = f2bf(v.z - bf2f(h2));
  short l3 = f2bf(v.w - bf2f(h3));
  ((short4*)xh)[i] = make_short4(h0, h1, h2, h3);
  ((short4*)xl)[i] = make_short4(l0, l1, l2, l3);
}

__global__ __launch_bounds__(256) void transw_kernel(
    const float* __restrict__ W, short* __restrict__ dh, short* __restrict__ dl) {
  __shared__ float tile[32][33];
  const int tx = threadIdx.x, ty = threadIdx.y;
  const int j0 = blockIdx.x * 32, k0 = blockIdx.y * 32;
  for (int i = ty; i < 32; i += 8)
    tile[i][tx] = W[(size_t)(k0 + i) * 1024 + j0 + tx];
  __syncthreads();
  for (int i = ty; i < 32; i += 8) {
    float v = tile[tx][i];
    size_t o = (size_t)(j0 + i) * 1024 + k0 + tx;
    short h = f2bf(v);
    dh[o] = h;
    if (dl) dl[o] = f2bf(v - bf2f(h));
  }
}

// -------------------------------- GEMM -------------------------------------

template <int SPLIT, int EPI>
__global__ __launch_bounds__(256) void gemm_kernel(
    const short* __restrict__ Asrc, const short* __restrict__ Alo,
    const short* __restrict__ Bsrc, const short* __restrict__ Blo,
    const float* __restrict__ biasA, const float* __restrict__ biasB,
    const float* __restrict__ ropeC, const float* __restrict__ ropeS,
    const int* __restrict__ lens,
    short* __restrict__ outH, short* __restrict__ outL,
    float* __restrict__ outF) {
  constexpr int NSLAB = SPLIT ? 4 : 2;
  __shared__ __align__(16) short smem[NSLAB * 4096];
  const int t = threadIdx.x;
  const int w = t >> 6, lane = t & 63;
  const int wr = w >> 1, wc = w & 1;
  const int fr = lane & 15, fg = lane >> 4;
  const int mtile = blockIdx.x, ntile = blockIdx.y;

  const int srow = (w << 4) + (lane >> 2);
  const int skel = (lane & 3) << 3;
  const size_t aBase = (size_t)(mtile * 128 + srow) * 1024 + skel;
  const size_t bBase = (size_t)(ntile * 128 + srow) * 1024 + skel;
  const int ldst = (w << 9) + (lane << 3);
  short* lA = &smem[0];
  short* lB = &smem[4096];

  f32x4 acc[4][4];
#pragma unroll
  for (int i = 0; i < 4; ++i)
#pragma unroll
    for (int j = 0; j < 4; ++j) {
      acc[i][j][0] = 0.f; acc[i][j][1] = 0.f; acc[i][j][2] = 0.f; acc[i][j][3] = 0.f;
    }

  for (int k0 = 0; k0 < 1024; k0 += 32) {
    gload16(Asrc + aBase + k0, lA + ldst);
    gload16(Asrc + aBase + k0 + 64 * 1024, lA + ldst + 2048);
    gload16(Bsrc + bBase + k0, lB + ldst);
    gload16(Bsrc + bBase + k0 + 64 * 1024, lB + ldst + 2048);
    if (SPLIT) {
      gload16(Alo + aBase + k0, lA + 8192 + ldst);
      gload16(Alo + aBase + k0 + 64 * 1024, lA + 8192 + ldst + 2048);
      gload16(Blo + bBase + k0, lB + 8192 + ldst);
      gload16(Blo + bBase + k0 + 64 * 1024, lB + 8192 + ldst + 2048);
    }
    __syncthreads();

    bf16x8 ah[4], bh[4], al[4], bl[4];
#pragma unroll
    for (int mi = 0; mi < 4; ++mi) {
      const int off = (wr * 64 + mi * 16 + fr) * 32 + fg * 8;
      ah[mi] = *(const bf16x8*)&lA[off];
      if (SPLIT) al[mi] = *(const bf16x8*)&lA[8192 + off];
    }
#pragma unroll
    for (int ni = 0; ni < 4; ++ni) {
      const int off = (wc * 64 + ni * 16 + fr) * 32 + fg * 8;
      bh[ni] = *(const bf16x8*)&lB[off];
      if (SPLIT) bl[ni] = *(const bf16x8*)&lB[8192 + off];
    }
#pragma unroll
    for (int mi = 0; mi < 4; ++mi)
#pragma unroll
      for (int ni = 0; ni < 4; ++ni) {
        acc[mi][ni] = mfma16(ah[mi], bh[ni], acc[mi][ni]);
        if (SPLIT) {
          acc[mi][ni] = mfma16(ah[mi], bl[ni], acc[mi][ni]);
          acc[mi][ni] = mfma16(al[mi], bh[ni], acc[mi][ni]);
        }
      }
    __syncthreads();
  }

  const int rowbase = mtile * 128 + wr * 64;
  const int colbase = ntile * 128 + wc * 64;

  if constexpr (EPI == 0) {
#pragma unroll
    for (int ni = 0; ni < 4; ++ni) {
      const int gcol = colbase + ni * 16 + fr;
      const int which = gcol >> 10, jj = gcol & 1023;
      const int hh = jj >> 6, dd = jj & 63;
      const float bias = which ? biasB[jj] : biasA[jj];
#pragma unroll
      for (int mi = 0; mi < 4; ++mi) {
#pragma unroll
        for (int r = 0; r < 4; ++r) {
          const int grow = rowbase + mi * 16 + fg * 4 + r;
          const int b = grow >> 11, n = grow & 2047;
          float val = acc[mi][ni][r] + bias;
          float part = __shfl_xor(val, 1);
          const size_t ro = (size_t)(b * 2048 + n) * 1024 + jj;
          const float c = ropeC[ro], s = ropeS[ro];
          float rot = (fr & 1) ? (val * c + part * s) : (val * c - part * s);
          if (!which) rot *= 1.44269504f;  // fold log2e into q (softmax in exp2)
          const short hi = f2bf(rot);
          const short lo = f2bf(rot - bf2f(hi));
          const size_t dst =
              ((size_t)((which * 2 + b) * 16 + hh) * 2048 + n) * 64 + dd;
          outH[dst] = hi;
          outL[dst] = lo;
        }
      }
    }
  } else if constexpr (EPI == 1) {
#pragma unroll
    for (int mi = 0; mi < 4; ++mi) {
#pragma unroll
      for (int r = 0; r < 4; ++r) {
        const int j = rowbase + mi * 16 + fg * 4 + r;
        const int hh = j >> 6, dd = j & 63;
        const float bias = biasA[j];
#pragma unroll
        for (int ni = 0; ni < 4; ++ni) {
          const int m = colbase + ni * 16 + fr;
          const int b = m >> 11, n = m & 2047;
          outH[((size_t)(b * 16 + hh) * 64 + dd) * 2048 + n] =
              f2bf(acc[mi][ni][r] + bias);
        }
      }
    }
  } else {
    const int b = rowbase >> 11;
    const int len = lens[b];
#pragma unroll
    for (int ni = 0; ni < 4; ++ni) {
      const int gcol = colbase + ni * 16 + fr;
      const float bias = biasA[gcol];
#pragma unroll
      for (int mi = 0; mi < 4; ++mi) {
#pragma unroll
        for (int r = 0; r < 4; ++r) {
          const int m = rowbase + mi * 16 + fg * 4 + r;
          const int n = m & 2047;
          float val = acc[mi][ni][r] + bias;
          if (n >= len) val = 0.f;
          outF[(size_t)m * 1024 + gcol] = val;
        }
      }
    }
  }
}

// ------------------------------ attention ----------------------------------
// grid (32 qtiles x 64 rows, 32 bh); 4 waves/block, wave = 16 q rows.
// Swapped QK^T: sacc = mfma(K, Q) -> S^T, col=q=lane&15 (lane-local softmax
// row), row=key=fg*4+r. K(hi/lo) and V^T staged in LDS (double-buffered,
// global_load_lds, XOR-swizzled via pre-swizzled global source). Counted
// vmcnt + raw barriers. Defer-max (THR=8), exp2 softmax (q pre-scaled).
// LDS: 2 x { Khi 4KB | Klo 4KB | V 4KB } + P 4x1KB = 28 KiB.
__global__ __launch_bounds__(256, 4) void attn_kernel(
    const short* __restrict__ qkh, const short* __restrict__ qkl,
    const short* __restrict__ vt, const int* __restrict__ lens,
    short* __restrict__ ctx) {
  __shared__ __align__(16) char lds[28672];
  const int t = threadIdx.x;
  const int w = t >> 6, lane = t & 63;
  const int fr = lane & 15, fg = lane >> 4;
  const int qtile = blockIdx.x, bh = blockIdx.y;
  const int b = bh >> 4, h = bh & 15;
  const int len = lens[b];
  const int q0 = qtile * 64 + w * 16;
  const size_t qoff = (size_t)(b * 16 + h) * 2048 * 64;
  const size_t koff = (size_t)((2 + b) * 16 + h) * 2048 * 64;
  const size_t voff = (size_t)(b * 16 + h) * 64 * 2048;

  // Q fragments (already scaled by log2e in the gemm epilogue)
  bf16x8 qh[2], ql[2];
#pragma unroll
  for (int s = 0; s < 2; ++s) {
    const size_t o = qoff + (size_t)(q0 + fr) * 64 + s * 32 + fg * 8;
    qh[s] = *(const bf16x8*)(qkh + o);
    ql[s] = *(const bf16x8*)(qkl + o);
  }

  // staging source addresses (pre-swizzled so LDS stays linear-dest)
  const int skey = t >> 3;                  // K tile row (key), 0..31
  const int soct = (t & 7) ^ (skey & 7);    // swizzled 16B slot within row
  const size_t kg = koff + (size_t)skey * 64 + soct * 8;
  const int sd = t >> 2;                    // V tile row (d), 0..63
  const int svo = (t & 3) ^ (sd & 3);
  const size_t vg = voff + (size_t)sd * 2048 + svo * 8;
  char* myl = lds + t * 16;
  char* pb = lds + 24576 + w * 1024;        // wave-private P tile [16][32]

  f32x4 o_acc[4];
#pragma unroll
  for (int dt = 0; dt < 4; ++dt) {
    o_acc[dt][0] = 0.f; o_acc[dt][1] = 0.f; o_acc[dt][2] = 0.f; o_acc[dt][3] = 0.f;
  }
  float mrun = -1e30f, lrun = 0.f;  // per-lane, row q = fr (replicated x4 fg)

#define STAGE(bi, k0_) do { \
    char* dst = myl + (bi) * 12288; \
    gload16(qkh + kg + (size_t)(k0_) * 64, dst); \
    gload16(qkl + kg + (size_t)(k0_) * 64, dst + 4096); \
    gload16(vt + vg + (k0_), dst + 8192); \
  } while (0)

  const int nkb = (len + 31) >> 5;
  STAGE(0, 0);

  for (int kb = 0; kb < nkb; ++kb) {
    const int cur = kb & 1;
    if (kb + 1 < nkb) {
      STAGE(cur ^ 1, (kb + 1) * 32);
      asm volatile("s_waitcnt vmcnt(3)" ::: "memory");
    } else {
      asm volatile("s_waitcnt vmcnt(0)" ::: "memory");
    }
    __builtin_amdgcn_s_barrier();

    const char* Kb = lds + cur * 12288;
    const char* Vb = Kb + 8192;

    f32x4 sacc[2];
#pragma unroll
    for (int ct = 0; ct < 2; ++ct) {
      sacc[ct][0] = 0.f; sacc[ct][1] = 0.f; sacc[ct][2] = 0.f; sacc[ct][3] = 0.f;
    }
    __builtin_amdgcn_s_setprio(1);
#pragma unroll
    for (int ct = 0; ct < 2; ++ct) {
      const int krow = ct * 16 + fr;
      const int swz = (krow & 7) << 4;
#pragma unroll
      for (int s = 0; s < 2; ++s) {
        const int off = (krow * 128 + s * 64 + fg * 16) ^ swz;
        const bf16x8 kh = *(const bf16x8*)(Kb + off);
        const bf16x8 kl = *(const bf16x8*)(Kb + 4096 + off);
        sacc[ct] = mfma16(kh, qh[s], sacc[ct]);
        sacc[ct] = mfma16(kl, qh[s], sacc[ct]);
        sacc[ct] = mfma16(kh, ql[s], sacc[ct]);
      }
    }
    __builtin_amdgcn_s_setprio(0);

    if ((kb == nkb - 1) && (len & 31)) {
#pragma unroll
      for (int ct = 0; ct < 2; ++ct)
#pragma unroll
        for (int r = 0; r < 4; ++r)
          if (kb * 32 + ct * 16 + fg * 4 + r >= len) sacc[ct][r] = NEGBIG;
    }

    // --- online softmax (log2 domain); rows are lane-local (q = fr) ---
    float mx = fmaxf(fmaxf(fmaxf(sacc[0][0], sacc[0][1]), fmaxf(sacc[0][2], sacc[0][3])),
                     fmaxf(fmaxf(sacc[1][0], sacc[1][1]), fmaxf(sacc[1][2], sacc[1][3])));
    mx = fmaxf(mx, __shfl_xor(mx, 16));
    mx = fmaxf(mx, __shfl_xor(mx, 32));
    if (!__all(mx <= mrun + 8.f)) {   // defer-max: rescale only on real growth
      const float mnew = fmaxf(mrun, mx);
      const float scq = exp2f(mrun - mnew);
      mrun = mnew;
      lrun *= scq;
      float scrow[4];
#pragma unroll
      for (int r = 0; r < 4; ++r) scrow[r] = __shfl(scq, fg * 4 + r);
#pragma unroll
      for (int dt = 0; dt < 4; ++dt) {
        o_acc[dt][0] *= scrow[0]; o_acc[dt][1] *= scrow[1];
        o_acc[dt][2] *= scrow[2]; o_acc[dt][3] *= scrow[3];
      }
    }
    float p[2][4];
#pragma unroll
    for (int ct = 0; ct < 2; ++ct)
#pragma unroll
      for (int r = 0; r < 4; ++r) p[ct][r] = exp2f(sacc[ct][r] - mrun);
    float ts = ((p[0][0] + p[0][1]) + (p[0][2] + p[0][3])) +
               ((p[1][0] + p[1][1]) + (p[1][2] + p[1][3]));
    ts += __shfl_xor(ts, 16);
    ts += __shfl_xor(ts, 32);
    lrun += ts;

    // --- P -> wave-private LDS (packed b64, swizzled), reread as A-frag ---
    const int pswz = (fr & 3) << 4;
#pragma unroll
    for (int ct = 0; ct < 2; ++ct) {
      uint2 pk;
      pk.x = pack2(p[ct][0], p[ct][1]);
      pk.y = pack2(p[ct][2], p[ct][3]);
      *(uint2*)(pb + ((fr * 64 + ct * 32 + fg * 8) ^ pswz)) = pk;
    }
    const bf16x8 pf = *(const bf16x8*)(pb + ((fr * 64 + fg * 16) ^ pswz));

    __builtin_amdgcn_s_setprio(1);
#pragma unroll
    for (int dt = 0; dt < 4; ++dt) {
      const int d = dt * 16 + fr;
      const int voffb = (d * 64 + fg * 16) ^ ((d & 3) << 4);
      const bf16x8 vf = *(const bf16x8*)(Vb + voffb);
      o_acc[dt] = mfma16(pf, vf, o_acc[dt]);
    }
    __builtin_amdgcn_s_setprio(0);

    asm volatile("" ::: "memory");
    __builtin_amdgcn_s_barrier();
  }
#undef STAGE

  float linv[4];
#pragma unroll
  for (int r = 0; r < 4; ++r) linv[r] = 1.f / __shfl(lrun, fg * 4 + r);
#pragma unroll
  for (int dt = 0; dt < 4; ++dt)
#pragma unroll
    for (int r = 0; r < 4; ++r) {
      const int n = q0 + fg * 4 + r;
      ctx[(size_t)(b * 2048 + n) * 1024 + h * 64 + dt * 16 + fr] =
          f2bf(o_acc[dt][r] * linv[r]);
    }
}

// ------------------------------ launcher -----------------------------------

extern "C" void kernel_launch(void* const* d_in, const int* in_sizes, int n_in,
                              void* d_out, int out_size, void* d_ws, size_t ws_size,
                              hipStream_t stream) {
  const float* x = (const float*)d_in[0];
  const float* rc = (const float*)d_in[1];
  const float* rs = (const float*)d_in[2];
  const int* lens = (const int*)d_in[3];
  const float* Wq = (const float*)d_in[4];
  const float* bq = (const float*)d_in[5];
  const float* Wk = (const float*)d_in[6];
  const float* bk = (const float*)d_in[7];
  const float* Wv = (const float*)d_in[8];
  const float* bv = (const float*)d_in[9];
  const float* Wo = (const float*)d_in[10];
  const float* bo = (const float*)d_in[11];
  float* out = (float*)d_out;

  char* ws = (char*)d_ws;
  const size_t MB = 1024 * 1024;
  short* XH = (short*)(ws + 0);
  short* XL = (short*)(ws + 8 * MB);
  short* WTH = (short*)(ws + 16 * MB);
  short* WTL = (short*)(ws + 22 * MB);
  short* WOT = (short*)(ws + 26 * MB);
  short* QKH = (short*)(ws + 28 * MB);
  short* QKL = (short*)(ws + 44 * MB);
  short* VT = (short*)(ws + 60 * MB);
  short* CTX = (short*)(ws + 68 * MB);

  split_x_kernel<<<4096, 256, 0, stream>>>(x, XH, XL);
  dim3 tb(32, 8), tg(32, 32);
  transw_kernel<<<tg, tb, 0, stream>>>(Wq, WTH, WTL);
  transw_kernel<<<tg, tb, 0, stream>>>(Wk, WTH + 1024 * 1024, WTL + 1024 * 1024);
  transw_kernel<<<tg, tb, 0, stream>>>(Wv, WTH + 2048 * 1024, nullptr);
  transw_kernel<<<tg, tb, 0, stream>>>(Wo, WOT, nullptr);

  gemm_kernel<1, 0><<<dim3(32, 16), 256, 0, stream>>>(
      XH, XL, WTH, WTL, bq, bk, rc, rs, nullptr, QKH, QKL, nullptr);
  gemm_kernel<0, 1><<<dim3(8, 32), 256, 0, stream>>>(
      WTH + (size_t)2048 * 1024, nullptr, XH, nullptr, bv, nullptr, nullptr,
      nullptr, nullptr, VT, nullptr, nullptr);
  attn_kernel<<<dim3(32, 32), 256, 0, stream>>>(QKH, QKL, VT, lens, CTX);
  gemm_kernel<0, 2><<<dim3(32, 8), 256, 0, stream>>>(
      CTX, nullptr, WOT, nullptr, bo, nullptr, nullptr, nullptr, lens, nullptr,
      nullptr, out);
}

// Round 3
// 173.424 us; speedup vs baseline: 2.7332x; 1.5388x over previous
//
#include <hip/hip_runtime.h>
#include <hip/hip_bf16.h>

// ---------------------------------------------------------------------------
// Attention (B=2,N=2048,D=1024,H=16,DH=64) on gfx950 — full-fp16 pipeline.
//   1. conv_x: x -> fp16
//   2. transw: W^T fp16 (Wq|Wk|Wv -> WT3, Wo -> WOT)
//   3. gemm<128,0>: q|k|v = x@W+b in ONE gemm; epilogue: rope (+log2e on q)
//      -> QK [2][B][H][N][64] fp16; v -> VT [B][H][64][N] fp16 (packed 8B)
//   4. attn: flash attn fp16; swapped QK^T (lane-local softmax rows),
//      LDS-staged K/V (double-buffered global_load_lds, XOR-swizzled),
//      defer-max, exp2 softmax.
//   5. gemm<64,2>: out = (ctx@Wo + bo) * query_mask, f32
// fp16 error budget: q/k storage noise -> logit sigma ~2.5e-3 -> out ~0.03.
// ---------------------------------------------------------------------------

typedef _Float16 f16x8 __attribute__((ext_vector_type(8)));
typedef float f32x4 __attribute__((ext_vector_type(4)));

#define NEGBIG (-1.0e9f)

__device__ inline f32x4 mfma16(f16x8 a, f16x8 b, f32x4 c) {
  return __builtin_amdgcn_mfma_f32_16x16x32_f16(a, b, c, 0, 0, 0);
}

__device__ inline void gload16(const void* g, void* l) {
  __builtin_amdgcn_global_load_lds(
      (const __attribute__((address_space(1))) void*)g,
      (__attribute__((address_space(3))) void*)l, 16, 0, 0);
}

// -------------------------------- prep -------------------------------------

__global__ __launch_bounds__(256) void conv_x_kernel(
    const float* __restrict__ x, _Float16* __restrict__ xh) {
  const int i = blockIdx.x * 256 + threadIdx.x;
  const float4 v = ((const float4*)x)[i];
  union { _Float16 h[4]; short4 s; } u;
  u.h[0] = (_Float16)v.x; u.h[1] = (_Float16)v.y;
  u.h[2] = (_Float16)v.z; u.h[3] = (_Float16)v.w;
  ((short4*)xh)[i] = u.s;
}

// W [1024 k][1024 j] f32 -> dh[j][k] fp16
__global__ void transw_kernel(const float* __restrict__ W,
                              _Float16* __restrict__ dh) {
  __shared__ float tile[32][33];
  const int tx = threadIdx.x, ty = threadIdx.y;
  const int j0 = blockIdx.x * 32, k0 = blockIdx.y * 32;
  for (int i = ty; i < 32; i += 8)
    tile[i][tx] = W[(size_t)(k0 + i) * 1024 + j0 + tx];
  __syncthreads();
  for (int i = ty; i < 32; i += 8)
    dh[(size_t)(j0 + i) * 1024 + k0 + tx] = (_Float16)tile[tx][i];
}

// -------------------------------- GEMM -------------------------------------
// C[m][j] = sum_k A[m][k]*B[j][k], both fp16 row-major ld=1024. TM x 128 tile,
// BK=32, 4 waves. EPI 0: QKV (rope -> QK, packed v^T -> VT). EPI 2: f32 out
// with query mask.

template <int TM, int EPI>
__global__ __launch_bounds__(256) void gemm_kernel(
    const _Float16* __restrict__ A, const _Float16* __restrict__ B,
    const float* __restrict__ bias0, const float* __restrict__ bias1,
    const float* __restrict__ bias2,
    const float* __restrict__ ropeC, const float* __restrict__ ropeS,
    const int* __restrict__ lens,
    _Float16* __restrict__ outQK, _Float16* __restrict__ outVT,
    float* __restrict__ outF) {
  constexpr int MI = TM / 32;  // acc rows per wave
  __shared__ __align__(16) _Float16 smem[(TM + 128) * 32];
  const int t = threadIdx.x;
  const int w = t >> 6, lane = t & 63;
  const int wr = w >> 1, wc = w & 1;
  const int fr = lane & 15, fg = lane >> 4;
  const int mtile = blockIdx.x, ntile = blockIdx.y;

  const int srow = t >> 2;
  const int skel = (t & 3) << 3;
  const size_t aBase = (size_t)(mtile * TM + srow) * 1024 + skel;
  const size_t bBase = (size_t)(ntile * 128 + srow) * 1024 + skel;
  const int ldst = t * 8;  // fp16 elems (16B per thread)
  _Float16* lA = &smem[0];
  _Float16* lB = &smem[TM * 32];

  f32x4 acc[MI][4];
#pragma unroll
  for (int i = 0; i < MI; ++i)
#pragma unroll
    for (int j = 0; j < 4; ++j) {
      acc[i][j][0] = 0.f; acc[i][j][1] = 0.f; acc[i][j][2] = 0.f; acc[i][j][3] = 0.f;
    }

  for (int k0 = 0; k0 < 1024; k0 += 32) {
    gload16(A + aBase + k0, lA + ldst);
    if constexpr (TM == 128) gload16(A + aBase + k0 + 64 * 1024, lA + ldst + 2048);
    gload16(B + bBase + k0, lB + ldst);
    gload16(B + bBase + k0 + 64 * 1024, lB + ldst + 2048);
    __syncthreads();

    f16x8 af[MI], bf[4];
#pragma unroll
    for (int mi = 0; mi < MI; ++mi)
      af[mi] = *(const f16x8*)&lA[(wr * (TM / 2) + mi * 16 + fr) * 32 + fg * 8];
#pragma unroll
    for (int ni = 0; ni < 4; ++ni)
      bf[ni] = *(const f16x8*)&lB[(wc * 64 + ni * 16 + fr) * 32 + fg * 8];
#pragma unroll
    for (int mi = 0; mi < MI; ++mi)
#pragma unroll
      for (int ni = 0; ni < 4; ++ni)
        acc[mi][ni] = mfma16(af[mi], bf[ni], acc[mi][ni]);
    __syncthreads();
  }

  const int rowbase = mtile * TM + wr * (TM / 2);
  const int colbase = ntile * 128 + wc * 64;

  if constexpr (EPI == 0) {
    const int which = colbase >> 10;  // 0=q 1=k 2=v (block-uniform)
    if (which < 2) {
      const float* bias = which ? bias1 : bias0;
#pragma unroll
      for (int ni = 0; ni < 4; ++ni) {
        const int gcol = colbase + ni * 16 + fr;
        const int jj = gcol & 1023;
        const int hh = jj >> 6, dd = jj & 63;
        const float bv = bias[jj];
#pragma unroll
        for (int mi = 0; mi < MI; ++mi) {
#pragma unroll
          for (int r = 0; r < 4; ++r) {
            const int grow = rowbase + mi * 16 + fg * 4 + r;
            const int b = grow >> 11, n = grow & 2047;
            float val = acc[mi][ni][r] + bv;
            float part = __shfl_xor(val, 1);
            const size_t ro = (size_t)(b * 2048 + n) * 1024 + jj;
            const float c = ropeC[ro], s = ropeS[ro];
            float rot = (fr & 1) ? (val * c + part * s) : (val * c - part * s);
            if (!which) rot *= 1.44269504f;  // log2e folded into q
            outQK[((size_t)((which * 2 + b) * 16 + hh) * 2048 + n) * 64 + dd] =
                (_Float16)rot;
          }
        }
      }
    } else {
#pragma unroll
      for (int ni = 0; ni < 4; ++ni) {
        const int gcol = colbase + ni * 16 + fr;
        const int jj = gcol & 1023;
        const int hh = jj >> 6, dd = jj & 63;
        const float bv = bias2[jj];
#pragma unroll
        for (int mi = 0; mi < MI; ++mi) {
          const int n0 = rowbase + mi * 16 + fg * 4;
          const int b = n0 >> 11, n = n0 & 2047;
          union { _Float16 h[4]; short4 s4; } u;
#pragma unroll
          for (int r = 0; r < 4; ++r) u.h[r] = (_Float16)(acc[mi][ni][r] + bv);
          *(short4*)(outVT + ((size_t)(b * 16 + hh) * 64 + dd) * 2048 + n) = u.s4;
        }
      }
    }
  } else {
    const int b = rowbase >> 11;
    const int len = lens[b];
#pragma unroll
    for (int ni = 0; ni < 4; ++ni) {
      const int gcol = colbase + ni * 16 + fr;
      const float bv = bias0[gcol];
#pragma unroll
      for (int mi = 0; mi < MI; ++mi) {
#pragma unroll
        for (int r = 0; r < 4; ++r) {
          const int m = rowbase + mi * 16 + fg * 4 + r;
          const int n = m & 2047;
          float val = acc[mi][ni][r] + bv;
          if (n >= len) val = 0.f;
          outF[(size_t)m * 1024 + gcol] = val;
        }
      }
    }
  }
}

// ------------------------------ attention ----------------------------------
// grid (32 qtiles x 64 rows, 32 bh); 4 waves/block, wave = 16 q rows.
// Swapped QK^T -> S^T: col=q=lane&15 (lane-local row), row=key=fg*4+r.
// K,V^T staged in LDS (double-buffered global_load_lds, XOR-swizzled via
// pre-swizzled source). Counted vmcnt + raw barriers. Defer-max, exp2.
// LDS: 2 x { K 4KB | V 4KB } + P 4x1KB = 20 KiB.
__global__ __launch_bounds__(256, 4) void attn_kernel(
    const _Float16* __restrict__ qk, const _Float16* __restrict__ vt,
    const int* __restrict__ lens, _Float16* __restrict__ ctx) {
  __shared__ __align__(16) char lds[20480];
  const int t = threadIdx.x;
  const int w = t >> 6, lane = t & 63;
  const int fr = lane & 15, fg = lane >> 4;
  const int qtile = blockIdx.x, bh = blockIdx.y;
  const int b = bh >> 4, h = bh & 15;
  const int len = lens[b];
  const int q0 = qtile * 64 + w * 16;
  const size_t qoff = (size_t)(b * 16 + h) * 2048 * 64;
  const size_t koff = (size_t)((2 + b) * 16 + h) * 2048 * 64;
  const size_t voff = (size_t)(b * 16 + h) * 64 * 2048;

  f16x8 qf[2];
#pragma unroll
  for (int s = 0; s < 2; ++s)
    qf[s] = *(const f16x8*)(qk + qoff + (size_t)(q0 + fr) * 64 + s * 32 + fg * 8);

  // staging sources (pre-swizzled so linear LDS dest lands swizzled data)
  const int skey = t >> 3;
  const int soct = (t & 7) ^ (skey & 7);
  const size_t kg = koff + (size_t)skey * 64 + soct * 8;
  const int sd = t >> 2;
  const int svo = (t & 3) ^ (sd & 3);
  const size_t vg = voff + (size_t)sd * 2048 + svo * 8;
  char* pb = lds + 16384 + w * 1024;  // wave-private P tile [16][32] fp16

  f32x4 o_acc[4];
#pragma unroll
  for (int dt = 0; dt < 4; ++dt) {
    o_acc[dt][0] = 0.f; o_acc[dt][1] = 0.f; o_acc[dt][2] = 0.f; o_acc[dt][3] = 0.f;
  }
  float mrun = -1e30f, lrun = 0.f;

#define STAGE(bi, k0_) do { \
    char* dst = lds + (bi) * 8192 + t * 16; \
    gload16(qk + kg + (size_t)(k0_) * 64, dst); \
    gload16(vt + vg + (k0_), dst + 4096); \
  } while (0)

  const int nkb = (len + 31) >> 5;
  STAGE(0, 0);

  for (int kb = 0; kb < nkb; ++kb) {
    const int cur = kb & 1;
    if (kb + 1 < nkb) {
      STAGE(cur ^ 1, (kb + 1) * 32);
      asm volatile("s_waitcnt vmcnt(2)" ::: "memory");
    } else {
      asm volatile("s_waitcnt vmcnt(0)" ::: "memory");
    }
    __builtin_amdgcn_s_barrier();

    const char* Kb = lds + cur * 8192;
    const char* Vb = Kb + 4096;

    f32x4 sacc[2];
#pragma unroll
    for (int ct = 0; ct < 2; ++ct) {
      sacc[ct][0] = 0.f; sacc[ct][1] = 0.f; sacc[ct][2] = 0.f; sacc[ct][3] = 0.f;
    }
    __builtin_amdgcn_s_setprio(1);
#pragma unroll
    for (int ct = 0; ct < 2; ++ct) {
      const int krow = ct * 16 + fr;
      const int swz = (krow & 7) << 4;
#pragma unroll
      for (int s = 0; s < 2; ++s) {
        const f16x8 kf = *(const f16x8*)(Kb + ((krow * 128 + s * 64 + fg * 16) ^ swz));
        sacc[ct] = mfma16(kf, qf[s], sacc[ct]);
      }
    }
    __builtin_amdgcn_s_setprio(0);

    if ((kb == nkb - 1) && (len & 31)) {
#pragma unroll
      for (int ct = 0; ct < 2; ++ct)
#pragma unroll
        for (int r = 0; r < 4; ++r)
          if (kb * 32 + ct * 16 + fg * 4 + r >= len) sacc[ct][r] = NEGBIG;
    }

    // --- online softmax (log2 domain), rows lane-local (q = fr) ---
    float mx = fmaxf(fmaxf(fmaxf(sacc[0][0], sacc[0][1]), fmaxf(sacc[0][2], sacc[0][3])),
                     fmaxf(fmaxf(sacc[1][0], sacc[1][1]), fmaxf(sacc[1][2], sacc[1][3])));
    mx = fmaxf(mx, __shfl_xor(mx, 16));
    mx = fmaxf(mx, __shfl_xor(mx, 32));
    if (!__all(mx <= mrun + 8.f)) {  // defer-max
      const float mnew = fmaxf(mrun, mx);
      const float scq = exp2f(mrun - mnew);
      mrun = mnew;
      lrun *= scq;
      float scrow[4];
#pragma unroll
      for (int r = 0; r < 4; ++r) scrow[r] = __shfl(scq, fg * 4 + r);
#pragma unroll
      for (int dt = 0; dt < 4; ++dt) {
        o_acc[dt][0] *= scrow[0]; o_acc[dt][1] *= scrow[1];
        o_acc[dt][2] *= scrow[2]; o_acc[dt][3] *= scrow[3];
      }
    }
    float p[2][4];
#pragma unroll
    for (int ct = 0; ct < 2; ++ct)
#pragma unroll
      for (int r = 0; r < 4; ++r) p[ct][r] = exp2f(sacc[ct][r] - mrun);
    float ts = ((p[0][0] + p[0][1]) + (p[0][2] + p[0][3])) +
               ((p[1][0] + p[1][1]) + (p[1][2] + p[1][3]));
    ts += __shfl_xor(ts, 16);
    ts += __shfl_xor(ts, 32);
    lrun += ts;

    // --- P -> wave-private LDS (fp16 packed b64, swizzled), reread as A ---
    const int pswz = (fr & 3) << 4;
#pragma unroll
    for (int ct = 0; ct < 2; ++ct) {
      union { _Float16 h[4]; uint2 u2; } pk;
      pk.h[0] = (_Float16)p[ct][0]; pk.h[1] = (_Float16)p[ct][1];
      pk.h[2] = (_Float16)p[ct][2]; pk.h[3] = (_Float16)p[ct][3];
      *(uint2*)(pb + ((fr * 64 + ct * 32 + fg * 8) ^ pswz)) = pk.u2;
    }
    const f16x8 pf = *(const f16x8*)(pb + ((fr * 64 + fg * 16) ^ pswz));

    __builtin_amdgcn_s_setprio(1);
#pragma unroll
    for (int dt = 0; dt < 4; ++dt) {
      const int d = dt * 16 + fr;
      const f16x8 vf = *(const f16x8*)(Vb + ((d * 64 + fg * 16) ^ ((d & 3) << 4)));
      o_acc[dt] = mfma16(pf, vf, o_acc[dt]);
    }
    __builtin_amdgcn_s_setprio(0);

    asm volatile("" ::: "memory");
    __builtin_amdgcn_s_barrier();
  }
#undef STAGE

  float linv[4];
#pragma unroll
  for (int r = 0; r < 4; ++r) linv[r] = 1.f / __shfl(lrun, fg * 4 + r);
#pragma unroll
  for (int dt = 0; dt < 4; ++dt)
#pragma unroll
    for (int r = 0; r < 4; ++r) {
      const int n = q0 + fg * 4 + r;
      ctx[(size_t)(b * 2048 + n) * 1024 + h * 64 + dt * 16 + fr] =
          (_Float16)(o_acc[dt][r] * linv[r]);
    }
}

// ------------------------------ launcher -----------------------------------

extern "C" void kernel_launch(void* const* d_in, const int* in_sizes, int n_in,
                              void* d_out, int out_size, void* d_ws, size_t ws_size,
                              hipStream_t stream) {
  const float* x = (const float*)d_in[0];
  const float* rc = (const float*)d_in[1];
  const float* rs = (const float*)d_in[2];
  const int* lens = (const int*)d_in[3];
  const float* Wq = (const float*)d_in[4];
  const float* bq = (const float*)d_in[5];
  const float* Wk = (const float*)d_in[6];
  const float* bk = (const float*)d_in[7];
  const float* Wv = (const float*)d_in[8];
  const float* bv = (const float*)d_in[9];
  const float* Wo = (const float*)d_in[10];
  const float* bo = (const float*)d_in[11];
  float* out = (float*)d_out;

  char* ws = (char*)d_ws;
  const size_t MB = 1024 * 1024;
  _Float16* XH = (_Float16*)(ws + 0);         // [4096][1024]          8 MB
  _Float16* WT3 = (_Float16*)(ws + 8 * MB);   // [3072 j][1024 k]      6 MB
  _Float16* WOT = (_Float16*)(ws + 14 * MB);  // [1024 j][1024 k]      2 MB
  _Float16* QK = (_Float16*)(ws + 16 * MB);   // [2][2][16][2048][64] 16 MB
  _Float16* VT = (_Float16*)(ws + 32 * MB);   // [2][16][64][2048]     8 MB
  _Float16* CTX = (_Float16*)(ws + 40 * MB);  // [4096][1024]          8 MB

  conv_x_kernel<<<4096, 256, 0, stream>>>(x, XH);
  dim3 tb(32, 8), tg(32, 32);
  transw_kernel<<<tg, tb, 0, stream>>>(Wq, WT3);
  transw_kernel<<<tg, tb, 0, stream>>>(Wk, WT3 + (size_t)1024 * 1024);
  transw_kernel<<<tg, tb, 0, stream>>>(Wv, WT3 + (size_t)2048 * 1024);
  transw_kernel<<<tg, tb, 0, stream>>>(Wo, WOT);

  // q|k|v in one gemm (rope + log2e on q; v -> VT transposed)
  gemm_kernel<128, 0><<<dim3(32, 24), 256, 0, stream>>>(
      XH, WT3, bq, bk, bv, rc, rs, nullptr, QK, VT, nullptr);
  attn_kernel<<<dim3(32, 32), 256, 0, stream>>>(QK, VT, lens, CTX);
  // out = (ctx @ Wo + bo) * query-mask
  gemm_kernel<64, 2><<<dim3(64, 8), 256, 0, stream>>>(
      CTX, WOT, bo, nullptr, nullptr, nullptr, nullptr, lens, nullptr, nullptr,
      out);
}

// Round 4
// 165.012 us; speedup vs baseline: 2.8726x; 1.0510x over previous
//
#include <hip/hip_runtime.h>
#include <hip/hip_bf16.h>

// ---------------------------------------------------------------------------
// Attention (B=2,N=2048,D=1024,H=16,DH=64) on gfx950 — full-fp16 pipeline.
//   1. prep: x -> fp16; Wq|Wk|Wv|Wo -> W^T fp16 (one fused kernel)
//   2. gemm<128,0>: q|k|v = x@W+b in ONE gemm; epilogue: rope (+log2e on q)
//      -> QK [2][B][H][N][64] fp16; v -> VT [B][H][64][N] fp16 (packed 8B)
//   3. attn: flash attn fp16; 2-wave blocks (32 q rows) for 8 blocks/CU,
//      swapped QK^T (lane-local softmax rows), LDS-staged K/V (double-
//      buffered global_load_lds, 2-way-max swizzles), defer-max, exp2
//      softmax, row-sum via ones-MFMA.
//   4. gemm<64,2>: out = (ctx@Wo + bo) * query_mask, f32
// ---------------------------------------------------------------------------

typedef _Float16 f16x8 __attribute__((ext_vector_type(8)));
typedef float f32x4 __attribute__((ext_vector_type(4)));

#define NEGBIG (-1.0e9f)

__device__ inline f32x4 mfma16(f16x8 a, f16x8 b, f32x4 c) {
  return __builtin_amdgcn_mfma_f32_16x16x32_f16(a, b, c, 0, 0, 0);
}

__device__ inline void gload16(const void* g, void* l) {
  __builtin_amdgcn_global_load_lds(
      (const __attribute__((address_space(1))) void*)g,
      (__attribute__((address_space(3))) void*)l, 16, 0, 0);
}

// -------------------------------- prep -------------------------------------
// z<4: W[z] [1024 k][1024 j] f32 -> wt + z*1M: [j][k] fp16 (transposed)
// z==4: x f32 -> fp16 (copy-cast), 1024 float4 per block
__global__ __launch_bounds__(256) void prep_kernel(
    const float* __restrict__ x, const float* __restrict__ Wq,
    const float* __restrict__ Wk, const float* __restrict__ Wv,
    const float* __restrict__ Wo, _Float16* __restrict__ xh,
    _Float16* __restrict__ wt) {
  __shared__ float tile[32][33];
  const int z = blockIdx.z;
  const int tx = threadIdx.x, ty = threadIdx.y;
  if (z == 4) {
    const int bid = blockIdx.y * 32 + blockIdx.x;
    const int t = ty * 32 + tx;
#pragma unroll
    for (int i = 0; i < 4; ++i) {
      const int o = bid * 1024 + i * 256 + t;
      const float4 v = ((const float4*)x)[o];
      union { _Float16 h[4]; short4 s; } u;
      u.h[0] = (_Float16)v.x; u.h[1] = (_Float16)v.y;
      u.h[2] = (_Float16)v.z; u.h[3] = (_Float16)v.w;
      ((short4*)xh)[o] = u.s;
    }
    return;
  }
  const float* W = (z == 0) ? Wq : (z == 1) ? Wk : (z == 2) ? Wv : Wo;
  _Float16* dh = wt + (size_t)z * 1024 * 1024;
  const int j0 = blockIdx.x * 32, k0 = blockIdx.y * 32;
  for (int i = ty; i < 32; i += 8)
    tile[i][tx] = W[(size_t)(k0 + i) * 1024 + j0 + tx];
  __syncthreads();
  for (int i = ty; i < 32; i += 8)
    dh[(size_t)(j0 + i) * 1024 + k0 + tx] = (_Float16)tile[tx][i];
}

// -------------------------------- GEMM -------------------------------------
// C[m][j] = sum_k A[m][k]*B[j][k], both fp16 row-major ld=1024. TM x 128 tile,
// BK=32, 4 waves. EPI 0: QKV (rope -> QK, packed v^T -> VT). EPI 2: f32 out
// with query mask.

template <int TM, int EPI>
__global__ __launch_bounds__(256) void gemm_kernel(
    const _Float16* __restrict__ A, const _Float16* __restrict__ B,
    const float* __restrict__ bias0, const float* __restrict__ bias1,
    const float* __restrict__ bias2,
    const float* __restrict__ ropeC, const float* __restrict__ ropeS,
    const int* __restrict__ lens,
    _Float16* __restrict__ outQK, _Float16* __restrict__ outVT,
    float* __restrict__ outF) {
  constexpr int MI = TM / 32;  // acc rows per wave
  __shared__ __align__(16) _Float16 smem[(TM + 128) * 32];
  const int t = threadIdx.x;
  const int w = t >> 6, lane = t & 63;
  const int wr = w >> 1, wc = w & 1;
  const int fr = lane & 15, fg = lane >> 4;
  const int mtile = blockIdx.x, ntile = blockIdx.y;

  const int srow = t >> 2;
  const int skel = (t & 3) << 3;
  const size_t aBase = (size_t)(mtile * TM + srow) * 1024 + skel;
  const size_t bBase = (size_t)(ntile * 128 + srow) * 1024 + skel;
  const int ldst = t * 8;  // fp16 elems (16B per thread)
  _Float16* lA = &smem[0];
  _Float16* lB = &smem[TM * 32];

  f32x4 acc[MI][4];
#pragma unroll
  for (int i = 0; i < MI; ++i)
#pragma unroll
    for (int j = 0; j < 4; ++j) {
      acc[i][j][0] = 0.f; acc[i][j][1] = 0.f; acc[i][j][2] = 0.f; acc[i][j][3] = 0.f;
    }

  for (int k0 = 0; k0 < 1024; k0 += 32) {
    gload16(A + aBase + k0, lA + ldst);
    if constexpr (TM == 128) gload16(A + aBase + k0 + 64 * 1024, lA + ldst + 2048);
    gload16(B + bBase + k0, lB + ldst);
    gload16(B + bBase + k0 + 64 * 1024, lB + ldst + 2048);
    __syncthreads();

    f16x8 af[MI], bf[4];
#pragma unroll
    for (int mi = 0; mi < MI; ++mi)
      af[mi] = *(const f16x8*)&lA[(wr * (TM / 2) + mi * 16 + fr) * 32 + fg * 8];
#pragma unroll
    for (int ni = 0; ni < 4; ++ni)
      bf[ni] = *(const f16x8*)&lB[(wc * 64 + ni * 16 + fr) * 32 + fg * 8];
#pragma unroll
    for (int mi = 0; mi < MI; ++mi)
#pragma unroll
      for (int ni = 0; ni < 4; ++ni)
        acc[mi][ni] = mfma16(af[mi], bf[ni], acc[mi][ni]);
    __syncthreads();
  }

  const int rowbase = mtile * TM + wr * (TM / 2);
  const int colbase = ntile * 128 + wc * 64;

  if constexpr (EPI == 0) {
    const int which = colbase >> 10;  // 0=q 1=k 2=v (block-uniform)
    if (which < 2) {
      const float* bias = which ? bias1 : bias0;
#pragma unroll
      for (int ni = 0; ni < 4; ++ni) {
        const int gcol = colbase + ni * 16 + fr;
        const int jj = gcol & 1023;
        const int hh = jj >> 6, dd = jj & 63;
        const float bv = bias[jj];
#pragma unroll
        for (int mi = 0; mi < MI; ++mi) {
#pragma unroll
          for (int r = 0; r < 4; ++r) {
            const int grow = rowbase + mi * 16 + fg * 4 + r;
            const int b = grow >> 11, n = grow & 2047;
            float val = acc[mi][ni][r] + bv;
            float part = __shfl_xor(val, 1);
            const size_t ro = (size_t)(b * 2048 + n) * 1024 + jj;
            const float c = ropeC[ro], s = ropeS[ro];
            float rot = (fr & 1) ? (val * c + part * s) : (val * c - part * s);
            if (!which) rot *= 1.44269504f;  // log2e folded into q
            outQK[((size_t)((which * 2 + b) * 16 + hh) * 2048 + n) * 64 + dd] =
                (_Float16)rot;
          }
        }
      }
    } else {
#pragma unroll
      for (int ni = 0; ni < 4; ++ni) {
        const int gcol = colbase + ni * 16 + fr;
        const int jj = gcol & 1023;
        const int hh = jj >> 6, dd = jj & 63;
        const float bv = bias2[jj];
#pragma unroll
        for (int mi = 0; mi < MI; ++mi) {
          const int n0 = rowbase + mi * 16 + fg * 4;
          const int b = n0 >> 11, n = n0 & 2047;
          union { _Float16 h[4]; short4 s4; } u;
#pragma unroll
          for (int r = 0; r < 4; ++r) u.h[r] = (_Float16)(acc[mi][ni][r] + bv);
          *(short4*)(outVT + ((size_t)(b * 16 + hh) * 64 + dd) * 2048 + n) = u.s4;
        }
      }
    }
  } else {
    const int b = rowbase >> 11;
    const int len = lens[b];
#pragma unroll
    for (int ni = 0; ni < 4; ++ni) {
      const int gcol = colbase + ni * 16 + fr;
      const float bv = bias0[gcol];
#pragma unroll
      for (int mi = 0; mi < MI; ++mi) {
#pragma unroll
        for (int r = 0; r < 4; ++r) {
          const int m = rowbase + mi * 16 + fg * 4 + r;
          const int n = m & 2047;
          float val = acc[mi][ni][r] + bv;
          if (n >= len) val = 0.f;
          outF[(size_t)m * 1024 + gcol] = val;
        }
      }
    }
  }
}

// ------------------------------ attention ----------------------------------
// grid (64 qtiles x 32 rows, 32 bh); 2 waves/block (128 thr), wave = 16 q
// rows -> 2048 blocks = 8/CU. Swapped QK^T -> S^T: col=q=lane&15 (lane-local
// row), row=key=fg*4+r. K,V^T staged in LDS (double-buffered global_load_lds,
// pre-swizzled source; K slot^=(row&7), V slot^=((d>>1)&3) for 2-way-max bank
// spread). Counted vmcnt + raw barriers. Defer-max, exp2 softmax, row-sum
// via ones-MFMA. LDS: 2 x { K 4KB | V 4KB } + P 2x1KB = 18 KiB.
__global__ __launch_bounds__(128, 4) void attn_kernel(
    const _Float16* __restrict__ qk, const _Float16* __restrict__ vt,
    const int* __restrict__ lens, _Float16* __restrict__ ctx) {
  __shared__ __align__(16) char lds[18432];
  const int t = threadIdx.x;
  const int w = t >> 6, lane = t & 63;
  const int fr = lane & 15, fg = lane >> 4;
  const int qtile = blockIdx.x, bh = blockIdx.y;
  const int b = bh >> 4, h = bh & 15;
  const int len = lens[b];
  const int q0 = qtile * 32 + w * 16;
  const size_t qoff = (size_t)(b * 16 + h) * 2048 * 64;
  const size_t koff = (size_t)((2 + b) * 16 + h) * 2048 * 64;
  const size_t voff = (size_t)(b * 16 + h) * 64 * 2048;

  f16x8 qf[2];
#pragma unroll
  for (int s = 0; s < 2; ++s)
    qf[s] = *(const f16x8*)(qk + qoff + (size_t)(q0 + fr) * 64 + s * 32 + fg * 8);

  f16x8 onef;
#pragma unroll
  for (int i = 0; i < 8; ++i) onef[i] = (_Float16)1.0f;

  // staging sources (pre-swizzled so linear LDS dest lands swizzled data)
  const int skey = t >> 3;                       // K row 0..15 (line0)
  const int soct = (t & 7) ^ (skey & 7);
  const size_t kg = koff + (size_t)skey * 64 + soct * 8;
  const int sd = t >> 2;                         // V row 0..31 (line0)
  const int svo = (t & 3) ^ ((sd >> 1) & 3);
  const size_t vg = voff + (size_t)sd * 2048 + svo * 8;
  char* pb = lds + 16384 + w * 1024;  // wave-private P tile [16][32] fp16

  f32x4 o_acc[4];
#pragma unroll
  for (int dt = 0; dt < 4; ++dt) {
    o_acc[dt][0] = 0.f; o_acc[dt][1] = 0.f; o_acc[dt][2] = 0.f; o_acc[dt][3] = 0.f;
  }
  f32x4 lacc;  // row-sum accumulator, row layout q = fg*4+r
  lacc[0] = 0.f; lacc[1] = 0.f; lacc[2] = 0.f; lacc[3] = 0.f;
  float mrun = -1e30f;  // per-lane, row q = fr (replicated x4 fg)

#define STAGE(bi, k0_) do { \
    char* dst = lds + (bi) * 8192 + t * 16; \
    gload16(qk + kg + (size_t)(k0_) * 64, dst); \
    gload16(qk + kg + (size_t)(k0_) * 64 + 1024, dst + 2048); \
    gload16(vt + vg + (k0_), dst + 4096); \
    gload16(vt + vg + (k0_) + 32 * 2048, dst + 6144); \
  } while (0)

  const int nkb = (len + 31) >> 5;
  STAGE(0, 0);

  for (int kb = 0; kb < nkb; ++kb) {
    const int cur = kb & 1;
    if (kb + 1 < nkb) {
      STAGE(cur ^ 1, (kb + 1) * 32);
      asm volatile("s_waitcnt vmcnt(4)" ::: "memory");
    } else {
      asm volatile("s_waitcnt vmcnt(0)" ::: "memory");
    }
    __builtin_amdgcn_s_barrier();

    const char* Kb = lds + cur * 8192;
    const char* Vb = Kb + 4096;

    f32x4 sacc[2];
#pragma unroll
    for (int ct = 0; ct < 2; ++ct) {
      sacc[ct][0] = 0.f; sacc[ct][1] = 0.f; sacc[ct][2] = 0.f; sacc[ct][3] = 0.f;
    }
    __builtin_amdgcn_s_setprio(1);
#pragma unroll
    for (int ct = 0; ct < 2; ++ct) {
      const int krow = ct * 16 + fr;
      const int swz = (krow & 7) << 4;
#pragma unroll
      for (int s = 0; s < 2; ++s) {
        const f16x8 kf = *(const f16x8*)(Kb + ((krow * 128 + s * 64 + fg * 16) ^ swz));
        sacc[ct] = mfma16(kf, qf[s], sacc[ct]);
      }
    }
    __builtin_amdgcn_s_setprio(0);

    if ((kb == nkb - 1) && (len & 31)) {
#pragma unroll
      for (int ct = 0; ct < 2; ++ct)
#pragma unroll
        for (int r = 0; r < 4; ++r)
          if (kb * 32 + ct * 16 + fg * 4 + r >= len) sacc[ct][r] = NEGBIG;
    }

    // --- online softmax (log2 domain), rows lane-local (q = fr) ---
    float mx = fmaxf(fmaxf(fmaxf(sacc[0][0], sacc[0][1]), fmaxf(sacc[0][2], sacc[0][3])),
                     fmaxf(fmaxf(sacc[1][0], sacc[1][1]), fmaxf(sacc[1][2], sacc[1][3])));
    mx = fmaxf(mx, __shfl_xor(mx, 16));
    mx = fmaxf(mx, __shfl_xor(mx, 32));
    if (!__all(mx <= mrun + 8.f)) {  // defer-max
      const float mnew = fmaxf(mrun, mx);
      const float scq = exp2f(mrun - mnew);
      mrun = mnew;
      float scrow[4];
#pragma unroll
      for (int r = 0; r < 4; ++r) scrow[r] = __shfl(scq, fg * 4 + r);
      lacc[0] *= scrow[0]; lacc[1] *= scrow[1];
      lacc[2] *= scrow[2]; lacc[3] *= scrow[3];
#pragma unroll
      for (int dt = 0; dt < 4; ++dt) {
        o_acc[dt][0] *= scrow[0]; o_acc[dt][1] *= scrow[1];
        o_acc[dt][2] *= scrow[2]; o_acc[dt][3] *= scrow[3];
      }
    }
    float p[2][4];
#pragma unroll
    for (int ct = 0; ct < 2; ++ct)
#pragma unroll
      for (int r = 0; r < 4; ++r) p[ct][r] = exp2f(sacc[ct][r] - mrun);

    // --- P -> wave-private LDS (fp16 packed b64, swizzled), reread as A ---
    const int pswz = ((fr >> 1) & 3) << 4;
#pragma unroll
    for (int ct = 0; ct < 2; ++ct) {
      union { _Float16 h[4]; uint2 u2; } pk;
      pk.h[0] = (_Float16)p[ct][0]; pk.h[1] = (_Float16)p[ct][1];
      pk.h[2] = (_Float16)p[ct][2]; pk.h[3] = (_Float16)p[ct][3];
      *(uint2*)(pb + ((fr * 64 + ct * 32 + fg * 8) ^ pswz)) = pk.u2;
    }
    const f16x8 pf = *(const f16x8*)(pb + ((fr * 64 + fg * 16) ^ pswz));

    __builtin_amdgcn_s_setprio(1);
#pragma unroll
    for (int dt = 0; dt < 4; ++dt) {
      const int d = dt * 16 + fr;
      const f16x8 vf =
          *(const f16x8*)(Vb + ((d * 64 + (fg ^ ((d >> 1) & 3)) * 16)));
      o_acc[dt] = mfma16(pf, vf, o_acc[dt]);
    }
    lacc = mfma16(pf, onef, lacc);  // row-sums, layout q = fg*4+r
    __builtin_amdgcn_s_setprio(0);

    asm volatile("" ::: "memory");
    __builtin_amdgcn_s_barrier();
  }
#undef STAGE

  float linv[4];
#pragma unroll
  for (int r = 0; r < 4; ++r) linv[r] = 1.f / lacc[r];
#pragma unroll
  for (int dt = 0; dt < 4; ++dt)
#pragma unroll
    for (int r = 0; r < 4; ++r) {
      const int n = q0 + fg * 4 + r;
      ctx[(size_t)(b * 2048 + n) * 1024 + h * 64 + dt * 16 + fr] =
          (_Float16)(o_acc[dt][r] * linv[r]);
    }
}

// ------------------------------ launcher -----------------------------------

extern "C" void kernel_launch(void* const* d_in, const int* in_sizes, int n_in,
                              void* d_out, int out_size, void* d_ws, size_t ws_size,
                              hipStream_t stream) {
  const float* x = (const float*)d_in[0];
  const float* rc = (const float*)d_in[1];
  const float* rs = (const float*)d_in[2];
  const int* lens = (const int*)d_in[3];
  const float* Wq = (const float*)d_in[4];
  const float* bq = (const float*)d_in[5];
  const float* Wk = (const float*)d_in[6];
  const float* bk = (const float*)d_in[7];
  const float* Wv = (const float*)d_in[8];
  const float* bv = (const float*)d_in[9];
  const float* Wo = (const float*)d_in[10];
  const float* bo = (const float*)d_in[11];
  float* out = (float*)d_out;

  char* ws = (char*)d_ws;
  const size_t MB = 1024 * 1024;
  _Float16* XH = (_Float16*)(ws + 0);        // [4096][1024]          8 MB
  _Float16* WT = (_Float16*)(ws + 8 * MB);   // [4][1024 j][1024 k]   8 MB
  _Float16* QK = (_Float16*)(ws + 16 * MB);  // [2][2][16][2048][64] 16 MB
  _Float16* VT = (_Float16*)(ws + 32 * MB);  // [2][16][64][2048]     8 MB
  _Float16* CTX = (_Float16*)(ws + 40 * MB); // [4096][1024]          8 MB

  prep_kernel<<<dim3(32, 32, 5), dim3(32, 8), 0, stream>>>(x, Wq, Wk, Wv, Wo,
                                                           XH, WT);
  // q|k|v in one gemm (rope + log2e on q; v -> VT transposed)
  gemm_kernel<128, 0><<<dim3(32, 24), 256, 0, stream>>>(
      XH, WT, bq, bk, bv, rc, rs, nullptr, QK, VT, nullptr);
  attn_kernel<<<dim3(64, 32), 128, 0, stream>>>(QK, VT, lens, CTX);
  // out = (ctx @ Wo + bo) * query-mask
  gemm_kernel<64, 2><<<dim3(64, 8), 256, 0, stream>>>(
      CTX, WT + (size_t)3 * 1024 * 1024, bo, nullptr, nullptr, nullptr,
      nullptr, lens, nullptr, nullptr, out);
}